// Round 1
// baseline (216.039 us; speedup 1.0000x reference)
//
#include <hip/hip_runtime.h>

// Problem constants (B=64, C=512, H=W=32 -> HW=1024)
#define B_  64
#define C_  512
#define HW_ 1024
#define NCHUNK 16
#define CPC (C_ / NCHUNK)   // 32 channels per chunk

__device__ __forceinline__ float waveReduceSum(float v) {
    #pragma unroll
    for (int off = 32; off > 0; off >>= 1) v += __shfl_xor(v, off);
    return v;
}

__device__ __forceinline__ float waveReduceMax(float v) {
    #pragma unroll
    for (int off = 32; off > 0; off >>= 1) v = fmaxf(v, __shfl_xor(v, off));
    return v;
}

// ---------------------------------------------------------------------------
// Kernel 1: partial channel dot-products.
// grid = B*NCHUNK blocks, 256 threads. Block (b, chunk) computes, for all
// 1024 hw positions, sum over its 32 channels of l[b,c,hw]*w[c].
// Thread t owns hw = 4t..4t+3 (one float4). Coalesced: consecutive threads
// read consecutive float4s within a channel row.
// ---------------------------------------------------------------------------
__global__ __launch_bounds__(256) void k1_partial_dot(
        const float* __restrict__ l,
        const float* __restrict__ w,
        float* __restrict__ part) {
    const int blk   = blockIdx.x;
    const int b     = blk / NCHUNK;
    const int chunk = blk % NCHUNK;
    const int tid   = threadIdx.x;

    const float4* l4 = reinterpret_cast<const float4*>(
        l + ((size_t)b * C_ + (size_t)chunk * CPC) * HW_);

    float4 acc = {0.f, 0.f, 0.f, 0.f};
    #pragma unroll 8
    for (int i = 0; i < CPC; ++i) {
        const float wv = w[chunk * CPC + i];        // block-uniform -> scalar
        const float4 v = l4[(size_t)i * (HW_ / 4) + tid];
        acc.x = fmaf(v.x, wv, acc.x);
        acc.y = fmaf(v.y, wv, acc.y);
        acc.z = fmaf(v.z, wv, acc.z);
        acc.w = fmaf(v.w, wv, acc.w);
    }
    reinterpret_cast<float4*>(part)[(size_t)blk * (HW_ / 4) + tid] = acc;
}

// ---------------------------------------------------------------------------
// Kernel 2: reduce partials + gw[b], softmax over 1024 spatial positions.
// grid = B blocks, 1024 threads (thread == hw position).
// Writes c (logits) to d_out[0..B*HW) and a (softmax) to workspace.
// ---------------------------------------------------------------------------
__global__ __launch_bounds__(1024) void k2_softmax(
        const float* __restrict__ part,
        const float* __restrict__ g,
        const float* __restrict__ w,
        float* __restrict__ c_out,
        float* __restrict__ a_out) {
    __shared__ float lds[16];
    const int b   = blockIdx.x;
    const int tid = threadIdx.x;
    const int lane = tid & 63;
    const int wid  = tid >> 6;       // 16 waves

    // --- gw[b] = sum_c g[b,c]*w[c] (block reduce over first 512 threads) ---
    float p = (tid < C_) ? g[b * C_ + tid] * w[tid] : 0.f;
    p = waveReduceSum(p);
    if (lane == 0) lds[wid] = p;
    __syncthreads();
    if (wid == 0) {
        float x = (lane < 16) ? lds[lane] : 0.f;
        x = waveReduceSum(x);
        if (lane == 0) lds[0] = x;
    }
    __syncthreads();
    const float gw = lds[0];
    __syncthreads();

    // --- c value for this hw ---
    float cv = gw;
    #pragma unroll
    for (int k = 0; k < NCHUNK; ++k)
        cv += part[((size_t)b * NCHUNK + k) * HW_ + tid];

    // --- block max ---
    float m = waveReduceMax(cv);
    if (lane == 0) lds[wid] = m;
    __syncthreads();
    if (wid == 0) {
        float x = (lane < 16) ? lds[lane] : -3.402823466e+38f;
        x = waveReduceMax(x);
        if (lane == 0) lds[0] = x;
    }
    __syncthreads();
    m = lds[0];
    __syncthreads();

    // --- exp & block sum ---
    const float e = __expf(cv - m);
    float s = waveReduceSum(e);
    if (lane == 0) lds[wid] = s;
    __syncthreads();
    if (wid == 0) {
        float x = (lane < 16) ? lds[lane] : 0.f;
        x = waveReduceSum(x);
        if (lane == 0) lds[0] = x;
    }
    __syncthreads();
    s = lds[0];

    c_out[(size_t)b * HW_ + tid] = cv;
    a_out[(size_t)b * HW_ + tid] = e * __frcp_rn(s);
}

// ---------------------------------------------------------------------------
// Kernel 3: attention-weighted pooling g_out[b,c] = sum_hw l[b,c,hw]*a[b,hw].
// grid = B*32 blocks, 256 threads = 4 waves; each wave handles 4 channels.
// Each lane keeps its a-fragment (4 float4 = 16 hw values) in registers,
// reused across the wave's 4 channels. 64-lane shuffle reduce per channel.
// ---------------------------------------------------------------------------
__global__ __launch_bounds__(256) void k3_pool(
        const float* __restrict__ l,
        const float* __restrict__ a,
        float* __restrict__ gout) {
    const int blk  = blockIdx.x;
    const int b    = blk >> 5;       // /32
    const int cg   = blk & 31;       // 16-channel group
    const int lane = threadIdx.x & 63;
    const int wave = threadIdx.x >> 6;

    const float4* a4 = reinterpret_cast<const float4*>(a + (size_t)b * HW_);
    float4 av[4];
    #pragma unroll
    for (int i = 0; i < 4; ++i) av[i] = a4[i * 64 + lane];

    #pragma unroll
    for (int ch = 0; ch < 4; ++ch) {
        const int c = cg * 16 + wave * 4 + ch;
        const float4* l4 = reinterpret_cast<const float4*>(
            l + ((size_t)b * C_ + c) * HW_);
        float s = 0.f;
        #pragma unroll
        for (int i = 0; i < 4; ++i) {
            const float4 v = l4[i * 64 + lane];
            s = fmaf(v.x, av[i].x, s);
            s = fmaf(v.y, av[i].y, s);
            s = fmaf(v.z, av[i].z, s);
            s = fmaf(v.w, av[i].w, s);
        }
        s = waveReduceSum(s);
        if (lane == 0) gout[(size_t)b * C_ + c] = s;
    }
}

// ---------------------------------------------------------------------------
extern "C" void kernel_launch(void* const* d_in, const int* in_sizes, int n_in,
                              void* d_out, int out_size, void* d_ws, size_t ws_size,
                              hipStream_t stream) {
    const float* l = (const float*)d_in[0];   // [B, C, H, W]
    const float* g = (const float*)d_in[1];   // [B, C]
    const float* w = (const float*)d_in[2];   // [C]
    float* out = (float*)d_out;               // c: B*HW floats, then g_out: B*C floats

    float* part = (float*)d_ws;                        // B*NCHUNK*HW = 4 MiB
    float* a    = part + (size_t)B_ * NCHUNK * HW_;    // B*HW = 256 KiB

    k1_partial_dot<<<B_ * NCHUNK, 256, 0, stream>>>(l, w, part);
    k2_softmax<<<B_, 1024, 0, stream>>>(part, g, w, out, a);
    k3_pool<<<B_ * 32, 256, 0, stream>>>(l, a, out + (size_t)B_ * HW_);
}